// Round 2
// baseline (441.009 us; speedup 1.0000x reference)
//
#include <hip/hip_runtime.h>

// QuerySHLayerDeprecated: per-edge SH(lmax=2) + smooth radial basis embed.
// Inputs (float32 / int32 per reference):
//   d_in[0] = pos        f32[100000*3]
//   d_in[1] = query_pos  f32[8*1250*3] = f32[10000*3]
//   d_in[2] = edge_src   int32[4000000]   (index into query_pos rows)
//   d_in[3] = edge_dst   int32[4000000]   (index into pos rows)
// Output d_out (float32): edge_sh[4M*9] then edge_embed[4M*10], flat concat.

#define SQRT3F 1.7320508075688772f
// SMOOTH_C * sqrt(10) = 1.14136 * e^2 * sqrt(10)
#define EMB_K 26.6692997f

__global__ __launch_bounds__(256) void qsh_kernel(
    const float* __restrict__ pos,
    const float* __restrict__ qpos,
    const int* __restrict__ esrc,
    const int* __restrict__ edst,
    float* __restrict__ out_sh,
    float* __restrict__ out_emb,
    int n)
{
    int e = blockIdx.x * blockDim.x + threadIdx.x;
    if (e >= n) return;

    int s = esrc[e];
    int d = edst[e];

    float ax = qpos[3 * s + 0];
    float ay = qpos[3 * s + 1];
    float az = qpos[3 * s + 2];
    float bx = pos[3 * d + 0];
    float by = pos[3 * d + 1];
    float bz = pos[3 * d + 2];

    float vx = ax - bx, vy = ay - by, vz = az - bz;
    float r2 = vx * vx + vy * vy + vz * vz;
    float r = sqrtf(r2);
    float inv = (r > 0.0f) ? (1.0f / r) : 1.0f;
    float x = vx * inv, y = vy * inv, z = vz * inv;

    float* o = out_sh + (size_t)e * 9;
    o[0] = 1.0f;
    o[1] = x;
    o[2] = y;
    o[3] = z;
    o[4] = SQRT3F * x * z;
    o[5] = SQRT3F * x * y;
    o[6] = y * y - 0.5f * (x * x + z * z);
    o[7] = SQRT3F * y * z;
    o[8] = 0.5f * SQRT3F * (z * z - x * x);

    // embed: values_i = (i+1)/11, step = 1/11, t = 11*r
    // diff_i = t - (i+1); a = diff+1 = t - i; b = 1 - diff = (i+2) - t
    // f_i = C*sqrt(10) * exp(-(1/a + 1/b)) if a>0 && b>0 else 0
    float t = r * 11.0f;
    float* o2 = out_emb + (size_t)e * 10;
#pragma unroll
    for (int i = 0; i < 10; ++i) {
        float a = t - (float)i;
        float b = (float)(i + 2) - t;
        float f = 0.0f;
        if (a > 0.0f && b > 0.0f) {
            f = EMB_K * __expf(-(__frcp_rn(a) + __frcp_rn(b)));
        }
        o2[i] = f;
    }
}

extern "C" void kernel_launch(void* const* d_in, const int* in_sizes, int n_in,
                              void* d_out, int out_size, void* d_ws, size_t ws_size,
                              hipStream_t stream) {
    const float* pos  = (const float*)d_in[0];
    const float* qpos = (const float*)d_in[1];
    const int* esrc = (const int*)d_in[2];
    const int* edst = (const int*)d_in[3];
    int n = in_sizes[2];  // number of edges (4,000,000)

    float* out_sh  = (float*)d_out;
    float* out_emb = out_sh + (size_t)n * 9;

    int block = 256;
    int grid = (n + block - 1) / block;
    qsh_kernel<<<grid, block, 0, stream>>>(pos, qpos, esrc, edst, out_sh, out_emb, n);
}

// Round 3
// 375.152 us; speedup vs baseline: 1.1755x; 1.1755x over previous
//
#include <hip/hip_runtime.h>

// QuerySHLayerDeprecated: per-edge SH(lmax=2) + smooth radial basis embed.
// Inputs (float32 / int32 per reference):
//   d_in[0] = pos        f32[100000*3]
//   d_in[1] = query_pos  f32[10000*3]
//   d_in[2] = edge_src   int32[4000000]  (rows of query_pos)
//   d_in[3] = edge_dst   int32[4000000]  (rows of pos)
// Output d_out (float32): edge_sh[4M*9] then edge_embed[4M*10], flat concat.
//
// R2 post-mortem: per-thread strided stores (36/40 B lane stride) inflated
// store transactions ~10x -> 441 us vs ~55 us roofline. Fix: stage one
// block's outputs in LDS, write back fully coalesced.

#define SQRT3F 1.7320508075688772f
// SMOOTH_C * sqrt(10) = 1.14136 * e^2 * sqrt(10)
#define EMB_K 26.6692997f

__global__ __launch_bounds__(256) void qsh_kernel(
    const float* __restrict__ pos,
    const float* __restrict__ qpos,
    const int* __restrict__ esrc,
    const int* __restrict__ edst,
    float* __restrict__ out_sh,
    float* __restrict__ out_emb,
    int n)
{
    // [edge][19] staging; stride 19 (odd) -> ds_write lanes hit distinct
    // bank groups (2-way aliasing only, which is free on gfx950).
    __shared__ float lds[256 * 19];

    const int tid  = threadIdx.x;
    const int base = blockIdx.x * 256;
    const int e    = base + tid;
    const int count = min(256, n - base);

    if (tid < count) {
        int s = esrc[e];
        int d = edst[e];

        float ax = qpos[3 * s + 0];
        float ay = qpos[3 * s + 1];
        float az = qpos[3 * s + 2];
        float bx = pos[3 * d + 0];
        float by = pos[3 * d + 1];
        float bz = pos[3 * d + 2];

        float vx = ax - bx, vy = ay - by, vz = az - bz;
        float r2 = vx * vx + vy * vy + vz * vz;
        float r = sqrtf(r2);
        float inv = (r > 0.0f) ? (1.0f / r) : 1.0f;
        float x = vx * inv, y = vy * inv, z = vz * inv;

        float* l = lds + tid * 19;
        l[0] = 1.0f;
        l[1] = x;
        l[2] = y;
        l[3] = z;
        l[4] = SQRT3F * x * z;
        l[5] = SQRT3F * x * y;
        l[6] = y * y - 0.5f * (x * x + z * z);
        l[7] = SQRT3F * y * z;
        l[8] = 0.5f * SQRT3F * (z * z - x * x);

        // embed: t = 11*r; f_i = C*sqrt(10)*exp(-(1/(t-i) + 1/((i+2)-t)))
        // when t in (i, i+2), else 0.
        float t = r * 11.0f;
#pragma unroll
        for (int i = 0; i < 10; ++i) {
            float a = t - (float)i;
            float b = (float)(i + 2) - t;
            float f = 0.0f;
            if (a > 0.0f && b > 0.0f) {
                f = EMB_K * __expf(-(__frcp_rn(a) + __frcp_rn(b)));
            }
            l[9 + i] = f;
        }
    }
    __syncthreads();

    // Coalesced writeback: lane i writes dword i of a contiguous range.
    float* osh = out_sh + (size_t)base * 9;
    float* oem = out_emb + (size_t)base * 10;

    if (count == 256) {
#pragma unroll
        for (int k = 0; k < 9; ++k) {
            int idx = k * 256 + tid;
            int ee = idx / 9;
            int c  = idx - ee * 9;
            osh[idx] = lds[ee * 19 + c];
        }
#pragma unroll
        for (int k = 0; k < 10; ++k) {
            int idx = k * 256 + tid;
            int ee = idx / 10;
            int c  = idx - ee * 10;
            oem[idx] = lds[ee * 19 + 9 + c];
        }
    } else {
        int nsh = count * 9;
        for (int idx = tid; idx < nsh; idx += 256) {
            int ee = idx / 9;
            int c  = idx - ee * 9;
            osh[idx] = lds[ee * 19 + c];
        }
        int nem = count * 10;
        for (int idx = tid; idx < nem; idx += 256) {
            int ee = idx / 10;
            int c  = idx - ee * 10;
            oem[idx] = lds[ee * 19 + 9 + c];
        }
    }
}

extern "C" void kernel_launch(void* const* d_in, const int* in_sizes, int n_in,
                              void* d_out, int out_size, void* d_ws, size_t ws_size,
                              hipStream_t stream) {
    const float* pos  = (const float*)d_in[0];
    const float* qpos = (const float*)d_in[1];
    const int* esrc = (const int*)d_in[2];
    const int* edst = (const int*)d_in[3];
    int n = in_sizes[2];  // number of edges (4,000,000)

    float* out_sh  = (float*)d_out;
    float* out_emb = out_sh + (size_t)n * 9;

    int block = 256;
    int grid = (n + block - 1) / block;
    qsh_kernel<<<grid, block, 0, stream>>>(pos, qpos, esrc, edst, out_sh, out_emb, n);
}

// Round 4
// 361.051 us; speedup vs baseline: 1.2215x; 1.0391x over previous
//
#include <hip/hip_runtime.h>

// QuerySHLayerDeprecated: per-edge SH(lmax=2) + smooth radial basis embed.
// Inputs (float32 / int32 per reference):
//   d_in[0] = pos        f32[100000*3]
//   d_in[1] = query_pos  f32[10000*3]
//   d_in[2] = edge_src   int32[4000000]  (rows of query_pos)
//   d_in[3] = edge_dst   int32[4000000]  (rows of pos)
// Output d_out (float32): edge_sh[4M*9] then edge_embed[4M*10], flat concat.
//
// R3 post-mortem: store coalescing only bought 15% -> bottleneck is the
// random gather path (L1-miss bound) + L2 pollution from the 304MB output
// stream + wasted exp/rcp. This round: float4-padded gather tables in d_ws
// (2 dwordx4 gathers/edge instead of 6 dword), nontemporal index loads +
// output stores (protect table residency), 2-exp embed window shortcut,
// 2 edges/thread for ILP.

#define SQRT3F 1.7320508075688772f
// SMOOTH_C * sqrt(10) = 1.14136 * e^2 * sqrt(10)
#define EMB_K 26.6692997f
#define TPB 256
#define EPB 512   // edges per block (2 per thread: tid, tid+256)

__global__ __launch_bounds__(256) void pad_kernel(
    const float* __restrict__ pos, const float* __restrict__ qpos,
    float4* __restrict__ pos4, float4* __restrict__ qpos4,
    int npos, int nq)
{
    int i = blockIdx.x * blockDim.x + threadIdx.x;
    if (i < npos)
        pos4[i] = make_float4(pos[3 * i + 0], pos[3 * i + 1], pos[3 * i + 2], 0.f);
    if (i < nq)
        qpos4[i] = make_float4(qpos[3 * i + 0], qpos[3 * i + 1], qpos[3 * i + 2], 0.f);
}

// Compute one edge's 19 outputs into LDS row l[0..18].
__device__ __forceinline__ void compute_edge(
    float ax, float ay, float az, float bx, float by, float bz,
    float* __restrict__ l)
{
    float vx = ax - bx, vy = ay - by, vz = az - bz;
    float r2 = vx * vx + vy * vy + vz * vz;
    float r = sqrtf(r2);
    float inv = (r > 0.f) ? (1.f / r) : 1.f;
    float x = vx * inv, y = vy * inv, z = vz * inv;

    l[0] = 1.f;
    l[1] = x;
    l[2] = y;
    l[3] = z;
    l[4] = SQRT3F * x * z;
    l[5] = SQRT3F * x * y;
    l[6] = y * y - 0.5f * (x * x + z * z);
    l[7] = SQRT3F * y * z;
    l[8] = 0.5f * SQRT3F * (z * z - x * x);

    // embed: t = 11*r; basis i nonzero only for t in (i, i+2); windows
    // overlap by 1 => at most two nonzero, i in {floor(t)-1, floor(t)}.
#pragma unroll
    for (int j = 0; j < 10; ++j) l[9 + j] = 0.f;
    float t = r * 11.f;
    int k = (int)t;  // t >= 0, trunc == floor
#pragma unroll
    for (int m = 0; m < 2; ++m) {
        int j = k - 1 + m;
        float a = t - (float)j;
        float b = (float)(j + 2) - t;
        if (j >= 0 && j < 10 && a > 0.f && b > 0.f)
            l[9 + j] = EMB_K * __expf(-(__frcp_rn(a) + __frcp_rn(b)));
    }
}

template <bool PAD>
__global__ __launch_bounds__(256) void qsh_kernel(
    const float* __restrict__ pos,
    const float* __restrict__ qpos,
    const float4* __restrict__ pos4,
    const float4* __restrict__ qpos4,
    const int* __restrict__ esrc,
    const int* __restrict__ edst,
    float* __restrict__ out_sh,
    float* __restrict__ out_emb,
    int n)
{
    // [edge][19]; lane LDS-base stride = 19 words (odd) -> 2-way bank
    // aliasing only (free on gfx950).
    __shared__ float lds[EPB * 19];

    const int tid = threadIdx.x;
    const int base = blockIdx.x * EPB;
    const int count = min(EPB, n - base);

#pragma unroll
    for (int m = 0; m < 2; ++m) {
        int le = tid + m * TPB;      // local edge id
        if (le < count) {
            int e = base + le;
            // nontemporal: 32MB index streams must not thrash L1/L2
            int s = __builtin_nontemporal_load(esrc + e);
            int d = __builtin_nontemporal_load(edst + e);
            float ax, ay, az, bx, by, bz;
            if (PAD) {
                float4 q = qpos4[s];
                float4 p = pos4[d];
                ax = q.x; ay = q.y; az = q.z;
                bx = p.x; by = p.y; bz = p.z;
            } else {
                ax = qpos[3 * s + 0]; ay = qpos[3 * s + 1]; az = qpos[3 * s + 2];
                bx = pos[3 * d + 0];  by = pos[3 * d + 1];  bz = pos[3 * d + 2];
            }
            compute_edge(ax, ay, az, bx, by, bz, lds + le * 19);
        }
    }
    __syncthreads();

    // Coalesced nontemporal writeback: lane i writes dword i of a
    // contiguous range (don't let 304MB of output allocate in L1/L2).
    float* osh = out_sh + (size_t)base * 9;
    float* oem = out_emb + (size_t)base * 10;

    if (count == EPB) {
#pragma unroll
        for (int k2 = 0; k2 < 18; ++k2) {          // 512*9/256
            int idx = k2 * TPB + tid;
            int ee = idx / 9;
            int c = idx - ee * 9;
            __builtin_nontemporal_store(lds[ee * 19 + c], osh + idx);
        }
#pragma unroll
        for (int k2 = 0; k2 < 20; ++k2) {          // 512*10/256
            int idx = k2 * TPB + tid;
            int ee = idx / 10;
            int c = idx - ee * 10;
            __builtin_nontemporal_store(lds[ee * 19 + 9 + c], oem + idx);
        }
    } else {
        int nsh = count * 9;
        for (int idx = tid; idx < nsh; idx += TPB) {
            int ee = idx / 9;
            int c = idx - ee * 9;
            __builtin_nontemporal_store(lds[ee * 19 + c], osh + idx);
        }
        int nem = count * 10;
        for (int idx = tid; idx < nem; idx += TPB) {
            int ee = idx / 10;
            int c = idx - ee * 10;
            __builtin_nontemporal_store(lds[ee * 19 + 9 + c], oem + idx);
        }
    }
}

extern "C" void kernel_launch(void* const* d_in, const int* in_sizes, int n_in,
                              void* d_out, int out_size, void* d_ws, size_t ws_size,
                              hipStream_t stream) {
    const float* pos  = (const float*)d_in[0];
    const float* qpos = (const float*)d_in[1];
    const int* esrc = (const int*)d_in[2];
    const int* edst = (const int*)d_in[3];
    int npos = in_sizes[0] / 3;   // 100000
    int nq   = in_sizes[1] / 3;   // 10000
    int n    = in_sizes[2];       // 4,000,000 edges

    float* out_sh  = (float*)d_out;
    float* out_emb = out_sh + (size_t)n * 9;

    int grid = (n + EPB - 1) / EPB;

    size_t need = ((size_t)npos + (size_t)nq) * sizeof(float4);
    if (ws_size >= need) {
        float4* pos4  = (float4*)d_ws;
        float4* qpos4 = pos4 + npos;
        int pgrid = (max(npos, nq) + TPB - 1) / TPB;
        pad_kernel<<<pgrid, TPB, 0, stream>>>(pos, qpos, pos4, qpos4, npos, nq);
        qsh_kernel<true><<<grid, TPB, 0, stream>>>(
            pos, qpos, pos4, qpos4, esrc, edst, out_sh, out_emb, n);
    } else {
        qsh_kernel<false><<<grid, TPB, 0, stream>>>(
            pos, qpos, nullptr, nullptr, esrc, edst, out_sh, out_emb, n);
    }
}